// Round 1
// baseline (1024.682 us; speedup 1.0000x reference)
//
#include <hip/hip_runtime.h>

#define N_NODES 50000
#define E_EDGES 800000

// ---------------------------------------------------------------------------
// Edge layer 1: e1 = (edge_attr*w) @ We1.T + be1  (16 -> 64)
// m = relu(x[src] + e1); atomicAdd(agg1[dst], m)
// One wave per edge; lane = output dim d in [0,64).
// ---------------------------------------------------------------------------
__global__ __launch_bounds__(256) void k_edge1(
    const int* __restrict__ ei, const float* __restrict__ eattr,
    const float* __restrict__ ew, const float* __restrict__ We1,
    const float* __restrict__ be1, const float* __restrict__ x,
    float* __restrict__ agg1)
{
    const int lane = threadIdx.x & 63;
    const int wid  = (int)((blockIdx.x * blockDim.x + threadIdx.x) >> 6);
    const int nw   = (int)((gridDim.x * blockDim.x) >> 6);

    // Per-lane weight row (16 floats -> 16 VGPRs), loaded once.
    float wr[16];
#pragma unroll
    for (int k = 0; k < 16; ++k) wr[k] = We1[lane * 16 + k];
    const float bias = be1[lane];

    for (int e = wid; e < E_EDGES; e += nw) {
        const int eu = __builtin_amdgcn_readfirstlane(e);
        const int src = ei[eu];
        const int dst = ei[E_EDGES + eu];
        const float w = ew[eu];
        const float4* ea4 = (const float4*)(eattr + (size_t)eu * 16);
        const float4 a0 = ea4[0], a1 = ea4[1], a2 = ea4[2], a3 = ea4[3];
        float dot = a0.x * wr[0] + a0.y * wr[1] + a0.z * wr[2] + a0.w * wr[3]
                  + a1.x * wr[4] + a1.y * wr[5] + a1.z * wr[6] + a1.w * wr[7]
                  + a2.x * wr[8] + a2.y * wr[9] + a2.z * wr[10] + a2.w * wr[11]
                  + a3.x * wr[12] + a3.y * wr[13] + a3.z * wr[14] + a3.w * wr[15];
        const float e1 = fmaf(w, dot, bias);
        float m = x[(size_t)src * 64 + lane] + e1;
        m = m > 0.f ? m : 0.f;
        atomicAdd(agg1 + (size_t)dst * 64 + lane, m);
    }
}

// ---------------------------------------------------------------------------
// Edge layer 2: e2 = (edge_attr*w) @ We2.T + be2  (16 -> 128)
// m = relu(h1[src] + e2); atomicAdd(agg2[dst], m)
// One wave per edge; lane handles dims d and d+64.
// ---------------------------------------------------------------------------
__global__ __launch_bounds__(256) void k_edge2(
    const int* __restrict__ ei, const float* __restrict__ eattr,
    const float* __restrict__ ew, const float* __restrict__ We2,
    const float* __restrict__ be2, const float* __restrict__ h1,
    float* __restrict__ agg2)
{
    const int lane = threadIdx.x & 63;
    const int wid  = (int)((blockIdx.x * blockDim.x + threadIdx.x) >> 6);
    const int nw   = (int)((gridDim.x * blockDim.x) >> 6);

    float wrA[16], wrB[16];
#pragma unroll
    for (int k = 0; k < 16; ++k) wrA[k] = We2[lane * 16 + k];
#pragma unroll
    for (int k = 0; k < 16; ++k) wrB[k] = We2[(lane + 64) * 16 + k];
    const float biasA = be2[lane];
    const float biasB = be2[lane + 64];

    for (int e = wid; e < E_EDGES; e += nw) {
        const int eu = __builtin_amdgcn_readfirstlane(e);
        const int src = ei[eu];
        const int dst = ei[E_EDGES + eu];
        const float w = ew[eu];
        const float4* ea4 = (const float4*)(eattr + (size_t)eu * 16);
        const float4 a0 = ea4[0], a1 = ea4[1], a2 = ea4[2], a3 = ea4[3];
        float dA = a0.x * wrA[0] + a0.y * wrA[1] + a0.z * wrA[2] + a0.w * wrA[3]
                 + a1.x * wrA[4] + a1.y * wrA[5] + a1.z * wrA[6] + a1.w * wrA[7]
                 + a2.x * wrA[8] + a2.y * wrA[9] + a2.z * wrA[10] + a2.w * wrA[11]
                 + a3.x * wrA[12] + a3.y * wrA[13] + a3.z * wrA[14] + a3.w * wrA[15];
        float dB = a0.x * wrB[0] + a0.y * wrB[1] + a0.z * wrB[2] + a0.w * wrB[3]
                 + a1.x * wrB[4] + a1.y * wrB[5] + a1.z * wrB[6] + a1.w * wrB[7]
                 + a2.x * wrB[8] + a2.y * wrB[9] + a2.z * wrB[10] + a2.w * wrB[11]
                 + a3.x * wrB[12] + a3.y * wrB[13] + a3.z * wrB[14] + a3.w * wrB[15];
        const float e2A = fmaf(w, dA, biasA);
        const float e2B = fmaf(w, dB, biasB);
        float mA = h1[(size_t)src * 128 + lane] + e2A;
        float mB = h1[(size_t)src * 128 + 64 + lane] + e2B;
        mA = mA > 0.f ? mA : 0.f;
        mB = mB > 0.f ? mB : 0.f;
        atomicAdd(agg2 + (size_t)dst * 128 + lane, mA);
        atomicAdd(agg2 + (size_t)dst * 128 + 64 + lane, mB);
    }
}

// ---------------------------------------------------------------------------
// Node MLP: hout = relu( relu((hin+agg) @ W1.T + b1) @ W2.T + b2 )
// W1: [128][KIN], W2: [128][128]. Both transposed into LDS.
// Block = 256 threads; per iteration processes an 8-node tile.
// Thread t -> (j = t&127, half = t>>7); each thread accumulates 4 nodes.
// Tile arrays use stride 12 (bank-spread + 16B-aligned float4).
// ---------------------------------------------------------------------------
#define TS 12   // tile stride

template<int KIN>
__global__ __launch_bounds__(256) void k_node_mlp(
    const float* __restrict__ hin, const float* __restrict__ agg,
    const float* __restrict__ W1, const float* __restrict__ b1,
    const float* __restrict__ W2, const float* __restrict__ b2,
    float* __restrict__ hout)
{
    extern __shared__ float lds[];
    float* W1t = lds;                    // [KIN][128]
    float* W2t = W1t + KIN * 128;        // [128][128]
    float* hT  = W2t + 128 * 128;        // [KIN][TS]
    float* t1T = hT + KIN * TS;          // [128][TS]

    const int tid = threadIdx.x;
    // transpose weights into LDS (one-time per block)
    for (int i = tid; i < 128 * KIN; i += 256) {
        const int j = i / KIN, k = i % KIN;
        W1t[k * 128 + j] = W1[i];
    }
    for (int i = tid; i < 128 * 128; i += 256) {
        const int j = i >> 7, k = i & 127;
        W2t[k * 128 + j] = W2[i];
    }
    const int j    = tid & 127;
    const int half = tid >> 7;
    const int n0   = half * 4;
    const float bb1 = b1[j];
    const float bb2 = b2[j];
    __syncthreads();

    const int ntiles = N_NODES / 8;
    for (int t = blockIdx.x; t < ntiles; t += gridDim.x) {
        const size_t base = (size_t)t * 8;
        // stage h tile: hT[k][n] = hin + agg
        for (int i = tid; i < 8 * KIN; i += 256) {
            const int n = i / KIN, k = i % KIN;
            const size_t gi = (base + n) * KIN + k;
            hT[k * TS + n] = hin[gi] + agg[gi];
        }
        __syncthreads();

        // phase 1: t1[j][n] = relu(sum_k h[n][k] * W1[j][k] + b1[j])
        float a0 = 0.f, a1 = 0.f, a2 = 0.f, a3 = 0.f;
#pragma unroll 8
        for (int k = 0; k < KIN; ++k) {
            const float wv = W1t[k * 128 + j];
            const float4 hv = *(const float4*)(hT + k * TS + n0);
            a0 = fmaf(wv, hv.x, a0);
            a1 = fmaf(wv, hv.y, a1);
            a2 = fmaf(wv, hv.z, a2);
            a3 = fmaf(wv, hv.w, a3);
        }
        a0 = fmaxf(a0 + bb1, 0.f);
        a1 = fmaxf(a1 + bb1, 0.f);
        a2 = fmaxf(a2 + bb1, 0.f);
        a3 = fmaxf(a3 + bb1, 0.f);
        *(float4*)(t1T + j * TS + n0) = make_float4(a0, a1, a2, a3);
        __syncthreads();

        // phase 2: hout[n][j] = relu(sum_k t1[n][k] * W2[j][k] + b2[j])
        float c0 = 0.f, c1 = 0.f, c2 = 0.f, c3 = 0.f;
#pragma unroll 8
        for (int k = 0; k < 128; ++k) {
            const float wv = W2t[k * 128 + j];
            const float4 tv = *(const float4*)(t1T + k * TS + n0);
            c0 = fmaf(wv, tv.x, c0);
            c1 = fmaf(wv, tv.y, c1);
            c2 = fmaf(wv, tv.z, c2);
            c3 = fmaf(wv, tv.w, c3);
        }
        c0 = fmaxf(c0 + bb2, 0.f);
        c1 = fmaxf(c1 + bb2, 0.f);
        c2 = fmaxf(c2 + bb2, 0.f);
        c3 = fmaxf(c3 + bb2, 0.f);
        hout[(base + n0 + 0) * 128 + j] = c0;
        hout[(base + n0 + 1) * 128 + j] = c1;
        hout[(base + n0 + 2) * 128 + j] = c2;
        hout[(base + n0 + 3) * 128 + j] = c3;
        __syncthreads();   // before hT/t1T are overwritten next tile
    }
}

// ---------------------------------------------------------------------------
// Output head: out[n][c] = sum_k h[n][k]*Wo[c][k] + bo[c]   (128 -> 100)
// ---------------------------------------------------------------------------
__global__ __launch_bounds__(256) void k_head(
    const float* __restrict__ h, const float* __restrict__ Wo,
    const float* __restrict__ bo, float* __restrict__ out)
{
    extern __shared__ float lds[];
    float* Wot = lds;               // [128][100]
    float* hT  = Wot + 128 * 100;   // [128][TS]

    const int tid = threadIdx.x;
    for (int i = tid; i < 100 * 128; i += 256) {
        const int c = i >> 7, k = i & 127;
        Wot[k * 100 + c] = Wo[i];
    }
    const int c    = tid & 127;
    const int half = tid >> 7;
    const int n0   = half * 4;
    const int cc   = (c < 100) ? c : 0;
    const float bias = bo[cc];
    __syncthreads();

    const int ntiles = N_NODES / 8;
    for (int t = blockIdx.x; t < ntiles; t += gridDim.x) {
        const size_t base = (size_t)t * 8;
        for (int i = tid; i < 8 * 128; i += 256) {
            const int n = i >> 7, k = i & 127;
            hT[k * TS + n] = h[(base + n) * 128 + k];
        }
        __syncthreads();

        float a0 = 0.f, a1 = 0.f, a2 = 0.f, a3 = 0.f;
#pragma unroll 8
        for (int k = 0; k < 128; ++k) {
            const float wv = Wot[k * 100 + cc];
            const float4 hv = *(const float4*)(hT + k * TS + n0);
            a0 = fmaf(wv, hv.x, a0);
            a1 = fmaf(wv, hv.y, a1);
            a2 = fmaf(wv, hv.z, a2);
            a3 = fmaf(wv, hv.w, a3);
        }
        if (c < 100) {
            out[(base + n0 + 0) * 100 + c] = a0 + bias;
            out[(base + n0 + 1) * 100 + c] = a1 + bias;
            out[(base + n0 + 2) * 100 + c] = a2 + bias;
            out[(base + n0 + 3) * 100 + c] = a3 + bias;
        }
        __syncthreads();
    }
}

// ---------------------------------------------------------------------------
extern "C" void kernel_launch(void* const* d_in, const int* in_sizes, int n_in,
                              void* d_out, int out_size, void* d_ws, size_t ws_size,
                              hipStream_t stream) {
    const float* x     = (const float*)d_in[0];
    const int*   ei    = (const int*)  d_in[1];
    const float* eattr = (const float*)d_in[2];
    const float* ew    = (const float*)d_in[3];
    const float* We1   = (const float*)d_in[4];
    const float* be1   = (const float*)d_in[5];
    const float* W11   = (const float*)d_in[6];
    const float* b11   = (const float*)d_in[7];
    const float* W12   = (const float*)d_in[8];
    const float* b12   = (const float*)d_in[9];
    const float* We2   = (const float*)d_in[10];
    const float* be2   = (const float*)d_in[11];
    const float* W21   = (const float*)d_in[12];
    const float* b21   = (const float*)d_in[13];
    const float* W22   = (const float*)d_in[14];
    const float* b22   = (const float*)d_in[15];
    const float* Wo    = (const float*)d_in[16];
    const float* bo    = (const float*)d_in[17];
    float* out = (float*)d_out;

    char* ws = (char*)d_ws;
    float* agg1 = (float*)(ws);                 // 50000*64*4  = 12,800,000 B
    float* agg2 = (float*)(ws + 12800000);      // 50000*128*4 = 25,600,000 B
    float* h1   = (float*)(ws + 38400000);      // 25,600,000 B
    float* h2   = (float*)(ws + 64000000);      // 25,600,000 B

    // zero the scatter accumulators (ws is poisoned 0xAA before every call)
    hipMemsetAsync(d_ws, 0, 38400000, stream);

    k_edge1<<<1024, 256, 0, stream>>>(ei, eattr, ew, We1, be1, x, agg1);

    const size_t lds1 = (size_t)(64 * 128 + 128 * 128 + 64 * TS + 128 * TS) * 4;
    k_node_mlp<64><<<512, 256, lds1, stream>>>(x, agg1, W11, b11, W12, b12, h1);

    k_edge2<<<1024, 256, 0, stream>>>(ei, eattr, ew, We2, be2, h1, agg2);

    const size_t lds2 = (size_t)(128 * 128 + 128 * 128 + 128 * TS + 128 * TS) * 4;
    k_node_mlp<128><<<512, 256, lds2, stream>>>(h1, agg2, W21, b21, W22, b22, h2);

    const size_t lds3 = (size_t)(128 * 100 + 128 * TS) * 4;
    k_head<<<512, 256, lds3, stream>>>(h2, Wo, bo, out);
}